// Round 1
// 8116.331 us; speedup vs baseline: 1.3935x; 1.3935x over previous
//
#include <hip/hip_runtime.h>
#include <hip/hip_bf16.h>
#include <stdint.h>
#include <stddef.h>

// Problem constants
#define Bsz 32
#define Ssz 96
#define Tsz 96
#define Esz 256
#define Hsz 512
#define Vsz 32000
#define Gsz 2048   // 4*H

typedef float f32x4 __attribute__((ext_vector_type(4)));
typedef short short8 __attribute__((ext_vector_type(8)));

__device__ __forceinline__ unsigned short f2bf(float f) {
  union { float f; unsigned u; } c; c.f = f;
  unsigned u = c.u;
  unsigned r = (u + 0x7FFFu + ((u >> 16) & 1u)) >> 16;  // RNE
  return (unsigned short)r;
}

__device__ __forceinline__ float sigm(float x) { return 1.0f / (1.0f + expf(-x)); }

// ---------------- embedding gather -> bf16: out[i][0:256] = bf16(emb[idx[i]][0:256]) ----------------
__global__ __launch_bounds__(64) void embed_bf16_k(const int* __restrict__ idx,
                                                   const float* __restrict__ emb,
                                                   unsigned short* __restrict__ out) {
  int i = blockIdx.x;
  int r = idx[i];
  const float4* s = (const float4*)(emb + (size_t)r * Esz);
  float4 v = s[threadIdx.x];
  ushort4 p;
  p.x = f2bf(v.x); p.y = f2bf(v.y); p.z = f2bf(v.z); p.w = f2bf(v.w);
  *(ushort4*)(out + (size_t)i * Esz + (threadIdx.x << 2)) = p;
}

// ---------------- fp32 GEMM (small M only): C[M,N] = A[M,K] @ W[N,K]^T + bias[N] ----------------
__global__ __launch_bounds__(256) void gemm_f32(const float* __restrict__ A,
                                                const float* __restrict__ W,
                                                const float* __restrict__ bias,
                                                float* __restrict__ C,
                                                int M, int N, int K) {
  __shared__ float As[16][68];
  __shared__ float Ws[16][68];
  int tid = threadIdx.x;
  int m0 = blockIdx.y << 6, n0 = blockIdx.x << 6;
  int tx = tid & 15, ty = tid >> 4;
  int lr = tid >> 2, lc = tid & 3;
  float acc[4][4];
#pragma unroll
  for (int i = 0; i < 4; i++)
#pragma unroll
    for (int j = 0; j < 4; j++) acc[i][j] = 0.f;

  for (int k0 = 0; k0 < K; k0 += 16) {
    float4 va = make_float4(0.f, 0.f, 0.f, 0.f);
    float4 vw = make_float4(0.f, 0.f, 0.f, 0.f);
    if (m0 + lr < M) va = *(const float4*)&A[(size_t)(m0 + lr) * K + k0 + (lc << 2)];
    if (n0 + lr < N) vw = *(const float4*)&W[(size_t)(n0 + lr) * K + k0 + (lc << 2)];
    __syncthreads();
    As[lc * 4 + 0][lr] = va.x; As[lc * 4 + 1][lr] = va.y;
    As[lc * 4 + 2][lr] = va.z; As[lc * 4 + 3][lr] = va.w;
    Ws[lc * 4 + 0][lr] = vw.x; Ws[lc * 4 + 1][lr] = vw.y;
    Ws[lc * 4 + 2][lr] = vw.z; Ws[lc * 4 + 3][lr] = vw.w;
    __syncthreads();
#pragma unroll
    for (int kk = 0; kk < 16; kk++) {
      float4 a4 = *(const float4*)&As[kk][ty << 2];
      float4 b4 = *(const float4*)&Ws[kk][tx << 2];
      float av[4] = {a4.x, a4.y, a4.z, a4.w};
      float bv[4] = {b4.x, b4.y, b4.z, b4.w};
#pragma unroll
      for (int i = 0; i < 4; i++)
#pragma unroll
        for (int j = 0; j < 4; j++) acc[i][j] = fmaf(av[i], bv[j], acc[i][j]);
    }
  }
#pragma unroll
  for (int i = 0; i < 4; i++) {
    int m = m0 + (ty << 2) + i;
    if (m < M) {
#pragma unroll
      for (int j = 0; j < 4; j++) {
        int n = n0 + (tx << 2) + j;
        C[(size_t)m * N + n] = acc[i][j] + bias[n];
      }
    }
  }
}

// ---------------- LSTM step ----------------
// One kernel launch per time step (kernel boundary = grid sync).
// Split-K across the wave: lanes 0..31 do k=[0,256), lanes 32..63 do k=[256,512),
// combined with one __shfl_xor(.,32). Halves the dependent FMA/load chain and
// doubles waves/CU vs the old layout.
// JPB (j per block) = blockDim.x/64;  thread: b = lane&31, ks = lane>>5, jl = tid>>6.
struct ScanDir {
  const float* xp;         // [B][T][4H]
  const float* U;          // [4H][H]
  const float* h_in;       // [B][H]
  float* h_out;            // [B][H]
  float* c;                // [B][H] (in-place)
  float* hs;               // fp32 seq out [B][T][hs_pitch] or null
  unsigned short* hs_bf;   // bf16 seq out (same indexing) or null
  float* hT;               // [B][1024] or null
  float* cT;               // [B][1024] or null
  int hs_off, hs_pitch, t, cat_off;
};

__global__ __launch_bounds__(256) void lstm_step_k(ScanDir d0, ScanDir d1, int last) {
  __shared__ float hbuf[Bsz][Hsz];  // 64KB, chunk-XOR-swizzled
  ScanDir d = (blockIdx.y == 0) ? d0 : d1;
  int tid = threadIdx.x;
  int nthr = blockDim.x;
  // cooperative stage of h_in (32*512 floats), swizzled by 16B chunk
  const float4* src = (const float4*)d.h_in;
  for (int i = tid; i < Bsz * Hsz / 4; i += nthr) {
    int row = i >> 7;
    int cc = i & 127;
    *(float4*)&hbuf[row][(cc ^ (row & 7)) << 2] = src[i];
  }
  __syncthreads();

  int lane = tid & 63;
  int b = lane & 31;
  int ks = lane >> 5;                 // 0/1 : K half
  int jl = tid >> 6;                  // 0..JPB-1
  int JPB = nthr >> 6;
  int j = blockIdx.x * JPB + jl;      // 0..511
  const float* U0 = d.U + (size_t)j * Hsz;
  const float* U1 = U0 + (size_t)Hsz * Hsz;
  const float* U2 = U0 + (size_t)2 * Hsz * Hsz;
  const float* U3 = U0 + (size_t)3 * Hsz * Hsz;
  float a0 = 0.f, a1 = 0.f, a2 = 0.f, a3 = 0.f;
  size_t xb = ((size_t)b * Tsz + d.t) * Gsz + j;
  if (ks == 0) {
    a0 = d.xp[xb];
    a1 = d.xp[xb + Hsz];
    a2 = d.xp[xb + 2 * Hsz];
    a3 = d.xp[xb + 3 * Hsz];
  }
  int bs = b & 7;
  int k0 = ks << 8;  // 0 or 256
#pragma unroll 8
  for (int kk = 0; kk < 256; kk += 4) {
    int k = k0 + kk;
    float4 h4 = *(const float4*)&hbuf[b][((k >> 2) ^ bs) << 2];
    float4 u0 = *(const float4*)&U0[k];
    float4 u1 = *(const float4*)&U1[k];
    float4 u2 = *(const float4*)&U2[k];
    float4 u3 = *(const float4*)&U3[k];
    a0 = fmaf(h4.x, u0.x, a0); a0 = fmaf(h4.y, u0.y, a0); a0 = fmaf(h4.z, u0.z, a0); a0 = fmaf(h4.w, u0.w, a0);
    a1 = fmaf(h4.x, u1.x, a1); a1 = fmaf(h4.y, u1.y, a1); a1 = fmaf(h4.z, u1.z, a1); a1 = fmaf(h4.w, u1.w, a1);
    a2 = fmaf(h4.x, u2.x, a2); a2 = fmaf(h4.y, u2.y, a2); a2 = fmaf(h4.z, u2.z, a2); a2 = fmaf(h4.w, u2.w, a2);
    a3 = fmaf(h4.x, u3.x, a3); a3 = fmaf(h4.y, u3.y, a3); a3 = fmaf(h4.z, u3.z, a3); a3 = fmaf(h4.w, u3.w, a3);
  }
  // combine K halves (intra-wave, xor over lane bit 5)
  a0 += __shfl_xor(a0, 32);
  a1 += __shfl_xor(a1, 32);
  a2 += __shfl_xor(a2, 32);
  a3 += __shfl_xor(a3, 32);
  if (ks == 0) {
    float ig = sigm(a0), fg = sigm(a1), gg = tanhf(a2), og = sigm(a3);
    float cold = d.c[(size_t)b * Hsz + j];
    float cn = fg * cold + ig * gg;
    float hn = og * tanhf(cn);
    d.c[(size_t)b * Hsz + j] = cn;
    d.h_out[(size_t)b * Hsz + j] = hn;
    size_t so = ((size_t)b * Tsz + d.t) * d.hs_pitch + d.hs_off + j;
    if (d.hs)    d.hs[so] = hn;
    if (d.hs_bf) d.hs_bf[so] = f2bf(hn);
    if (last && d.hT) {
      d.hT[(size_t)b * 1024 + d.cat_off + j] = hn;
      d.cT[(size_t)b * 1024 + d.cat_off + j] = cn;
    }
  }
}

// ---------------- fused attention: energy -> masked softmax -> context ----------------
__global__ __launch_bounds__(128) void attn_k(const float* __restrict__ y,
                                              const float* __restrict__ enc,
                                              const int* __restrict__ src_seq,
                                              float* __restrict__ ctx) {
  __shared__ float ebuf[Ssz];
  __shared__ float pbuf[Ssz];
  int bt = blockIdx.x;
  int b = bt / Tsz;
  int tid = threadIdx.x;
  const float* yrow = y + (size_t)bt * Hsz;
  if (tid < Ssz) {
    const float* er = enc + ((size_t)b * Ssz + tid) * Hsz;
    float acc = 0.f;
    for (int k = 0; k < Hsz; k += 4) {
      float4 a = *(const float4*)&yrow[k];
      float4 e4 = *(const float4*)&er[k];
      acc = fmaf(a.x, e4.x, acc); acc = fmaf(a.y, e4.y, acc);
      acc = fmaf(a.z, e4.z, acc); acc = fmaf(a.w, e4.w, acc);
    }
    ebuf[tid] = (src_seq[b * Ssz + tid] != 0) ? acc : -1e10f;
  }
  __syncthreads();
  float mx = -3e38f;
  for (int s = 0; s < Ssz; s++) mx = fmaxf(mx, ebuf[s]);
  if (tid < Ssz) pbuf[tid] = expf(ebuf[tid] - mx);
  __syncthreads();
  float sm = 0.f;
  for (int s = 0; s < Ssz; s++) sm += pbuf[s];
  float inv = 1.f / sm;
  for (int k = tid; k < Hsz; k += 128) {
    float acc = 0.f;
    for (int s = 0; s < Ssz; s++) acc = fmaf(pbuf[s], enc[((size_t)b * Ssz + s) * Hsz + k], acc);
    ctx[(size_t)bt * Hsz + k] = acc * inv;
  }
}

// ---------------- fp32 -> bf16 bulk convert ----------------
__global__ __launch_bounds__(256) void cvt_bf16_k(const float* __restrict__ src,
                                                  unsigned short* __restrict__ dst, int n4) {
  int i = blockIdx.x * 256 + threadIdx.x;
  if (i < n4) {
    float4 v = *(const float4*)&src[(size_t)i << 2];
    ushort4 p;
    p.x = f2bf(v.x); p.y = f2bf(v.y); p.z = f2bf(v.z); p.w = f2bf(v.w);
    *(ushort4*)&dst[(size_t)i << 2] = p;
  }
}

// ---------------- build combined = [y2, ctx] in bf16: [3072][1024] ----------------
__global__ __launch_bounds__(256) void build_comb_k(const float* __restrict__ y2,
                                                    const float* __restrict__ ctx,
                                                    unsigned short* __restrict__ dst) {
  int m = blockIdx.x;
  int k = threadIdx.x << 2;
  float4 v;
  if (k < Hsz) v = *(const float4*)&y2[(size_t)m * Hsz + k];
  else         v = *(const float4*)&ctx[(size_t)m * Hsz + (k - Hsz)];
  ushort4 p;
  p.x = f2bf(v.x); p.y = f2bf(v.y); p.z = f2bf(v.z); p.w = f2bf(v.w);
  *(ushort4*)&dst[(size_t)m * 1024 + k] = p;
}

// ---------------- bf16 MFMA GEMM: C[M,N] = A[M,K] @ W[N,K]^T + bias (fp32 out) ----------------
// 128x128 tile, BK=32, 4 waves. M%128==N%128==K%32==0.
__global__ __launch_bounds__(256) void gemm_bf16_k(const unsigned short* __restrict__ A,
                                                   const unsigned short* __restrict__ Wt,
                                                   const float* __restrict__ bias,
                                                   float* __restrict__ C,
                                                   int M, int N, int K) {
  __shared__ short As[128][40];  // pitch 40 shorts = 80B (16B aligned)
  __shared__ short Ws[128][40];
  int tid = threadIdx.x;
  int m0 = blockIdx.y << 7, n0 = blockIdx.x << 7;
  int r = tid >> 2, c = tid & 3;
  int lane = tid & 63, w = tid >> 6;
  int wm = (w >> 1) << 6, wn = (w & 1) << 6;
  int lr = lane & 15, quad = lane >> 4;

  f32x4 acc[4][4];
#pragma unroll
  for (int i = 0; i < 4; i++)
#pragma unroll
    for (int j = 0; j < 4; j++) {
      acc[i][j][0] = 0.f; acc[i][j][1] = 0.f; acc[i][j][2] = 0.f; acc[i][j][3] = 0.f;
    }

  const short* Ag = (const short*)A;
  const short* Wg = (const short*)Wt;
  for (int k0 = 0; k0 < K; k0 += 32) {
    __syncthreads();
    *(float4*)&As[r][c << 3]      = *(const float4*)&Ag[(size_t)(m0 + r) * K + k0 + (c << 3)];
    *(float4*)&As[r + 64][c << 3] = *(const float4*)&Ag[(size_t)(m0 + r + 64) * K + k0 + (c << 3)];
    *(float4*)&Ws[r][c << 3]      = *(const float4*)&Wg[(size_t)(n0 + r) * K + k0 + (c << 3)];
    *(float4*)&Ws[r + 64][c << 3] = *(const float4*)&Wg[(size_t)(n0 + r + 64) * K + k0 + (c << 3)];
    __syncthreads();
    short8 af[4], bf[4];
#pragma unroll
    for (int i = 0; i < 4; i++) af[i] = *(const short8*)&As[wm + (i << 4) + lr][quad << 3];
#pragma unroll
    for (int i = 0; i < 4; i++) bf[i] = *(const short8*)&Ws[wn + (i << 4) + lr][quad << 3];
#pragma unroll
    for (int mi = 0; mi < 4; mi++)
#pragma unroll
      for (int ni = 0; ni < 4; ni++)
        acc[mi][ni] = __builtin_amdgcn_mfma_f32_16x16x32_bf16(af[mi], bf[ni], acc[mi][ni], 0, 0, 0);
  }

  float bv[4];
#pragma unroll
  for (int ni = 0; ni < 4; ni++) bv[ni] = bias[n0 + wn + (ni << 4) + lr];
#pragma unroll
  for (int mi = 0; mi < 4; mi++) {
#pragma unroll
    for (int ni = 0; ni < 4; ni++) {
      int n = n0 + wn + (ni << 4) + lr;
      int mbase = m0 + wm + (mi << 4) + (quad << 2);
#pragma unroll
      for (int e = 0; e < 4; e++) {
        C[(size_t)(mbase + e) * N + n] = acc[mi][ni][e] + bv[ni];
      }
    }
  }
}

// ============================================================================
extern "C" void kernel_launch(void* const* d_in, const int* in_sizes, int n_in,
                              void* d_out, int out_size, void* d_ws, size_t ws_size,
                              hipStream_t stream) {
  const int*   src_seq = (const int*)d_in[0];
  const int*   trg_seq = (const int*)d_in[1];
  const float* src_emb = (const float*)d_in[2];
  const float* trg_emb = (const float*)d_in[3];
  const float* eW0f = (const float*)d_in[4];
  const float* eU0f = (const float*)d_in[5];
  const float* eb0f = (const float*)d_in[6];
  const float* eW0b = (const float*)d_in[7];
  const float* eU0b = (const float*)d_in[8];
  const float* eb0b = (const float*)d_in[9];
  const float* eW1f = (const float*)d_in[10];
  const float* eU1f = (const float*)d_in[11];
  const float* eb1f = (const float*)d_in[12];
  const float* eW1b = (const float*)d_in[13];
  const float* eU1b = (const float*)d_in[14];
  const float* eb1b = (const float*)d_in[15];
  const float* out_W = (const float*)d_in[16];
  const float* out_b = (const float*)d_in[17];
  const float* hpW = (const float*)d_in[18];
  const float* hpb = (const float*)d_in[19];
  const float* cpW = (const float*)d_in[20];
  const float* cpb = (const float*)d_in[21];
  const float* dW0 = (const float*)d_in[22];
  const float* dU0 = (const float*)d_in[23];
  const float* db0 = (const float*)d_in[24];
  const float* dW1 = (const float*)d_in[25];
  const float* dU1 = (const float*)d_in[26];
  const float* db1 = (const float*)d_in[27];
  const float* fcW = (const float*)d_in[28];
  const float* fcb = (const float*)d_in[29];
  float* out = (float*)d_out;

  // workspace carve-up (~176 MB total)
  char* ws = (char*)d_ws;
  size_t off = 0;
  auto alloc = [&](size_t bytes) -> void* {
    void* p = ws + off;
    off = (off + bytes + 255) & ~(size_t)255;
    return p;
  };
  const int BT = Bsz * Tsz;  // 3072
  unsigned short* x0b = (unsigned short*)alloc((size_t)BT * Esz * 2);
  unsigned short* y0b = (unsigned short*)alloc((size_t)BT * Esz * 2);
  float* xpA     = (float*)alloc((size_t)BT * Gsz * 4);
  float* xpB     = (float*)alloc((size_t)BT * Gsz * 4);
  unsigned short* x1b = (unsigned short*)alloc((size_t)BT * 1024 * 2);
  unsigned short* x2b = (unsigned short*)alloc((size_t)BT * 1024 * 2);
  unsigned short* y1b = (unsigned short*)alloc((size_t)BT * Hsz * 2);
  float* enc_out = (float*)alloc((size_t)BT * Hsz * 4);
  float* y2      = (float*)alloc((size_t)BT * Hsz * 4);
  float* ctxb    = (float*)alloc((size_t)BT * Hsz * 4);
  float* hT0     = (float*)alloc((size_t)Bsz * 1024 * 4);
  float* cT0     = (float*)alloc((size_t)Bsz * 1024 * 4);
  float* hT1     = (float*)alloc((size_t)Bsz * 1024 * 4);
  float* cT1     = (float*)alloc((size_t)Bsz * 1024 * 4);
  float* h00     = (float*)alloc((size_t)Bsz * Hsz * 4);
  float* c00     = (float*)alloc((size_t)Bsz * Hsz * 4);
  float* h01     = (float*)alloc((size_t)Bsz * Hsz * 4);
  float* c01     = (float*)alloc((size_t)Bsz * Hsz * 4);
  float* hA0     = (float*)alloc((size_t)Bsz * Hsz * 4);
  float* hB0     = (float*)alloc((size_t)Bsz * Hsz * 4);
  float* cS0     = (float*)alloc((size_t)Bsz * Hsz * 4);
  float* hA1     = (float*)alloc((size_t)Bsz * Hsz * 4);
  float* hB1     = (float*)alloc((size_t)Bsz * Hsz * 4);
  float* cS1     = (float*)alloc((size_t)Bsz * Hsz * 4);
  unsigned short* comb_bf = (unsigned short*)alloc((size_t)BT * 1024 * 2);
  unsigned short* fcw_bf  = (unsigned short*)alloc((size_t)Vsz * 1024 * 2);
  // bf16 weight mirrors (converted every call; ~10us)
  unsigned short* eW0f_b = (unsigned short*)alloc((size_t)Gsz * Esz * 2);
  unsigned short* eW0b_b = (unsigned short*)alloc((size_t)Gsz * Esz * 2);
  unsigned short* eW1f_b = (unsigned short*)alloc((size_t)Gsz * 1024 * 2);
  unsigned short* eW1b_b = (unsigned short*)alloc((size_t)Gsz * 1024 * 2);
  unsigned short* outW_b = (unsigned short*)alloc((size_t)Hsz * 1024 * 2);
  unsigned short* dW0_b  = (unsigned short*)alloc((size_t)Gsz * Esz * 2);
  unsigned short* dW1_b  = (unsigned short*)alloc((size_t)Gsz * Hsz * 2);

  auto gemm = [&](const float* A, const float* W, const float* bias, float* C,
                  int M, int N, int K) {
    gemm_f32<<<dim3(N / 64, (M + 63) / 64), 256, 0, stream>>>(A, W, bias, C, M, N, K);
  };
  auto bgemm = [&](const unsigned short* A, const unsigned short* W, const float* bias,
                   float* C, int M, int N, int K) {
    gemm_bf16_k<<<dim3(N / 128, M / 128), 256, 0, stream>>>(A, W, bias, C, M, N, K);
  };
  auto cvtw = [&](const float* src, unsigned short* dst, int n) {
    cvt_bf16_k<<<(n / 4 + 255) / 256, 256, 0, stream>>>(src, dst, n / 4);
  };

  const int STATE_BYTES = Bsz * Hsz * 4;  // 64KB

  auto enc_scan = [&](const float* xpf, const float* Uf, const float* xpb, const float* Ub,
                      unsigned short* hs_bf, float* hTc, float* cTc) {
    hipMemsetAsync(hA0, 0, STATE_BYTES, stream);
    hipMemsetAsync(cS0, 0, STATE_BYTES, stream);
    hipMemsetAsync(hA1, 0, STATE_BYTES, stream);
    hipMemsetAsync(cS1, 0, STATE_BYTES, stream);
    for (int s = 0; s < Ssz; s++) {
      float* hin0 = (s & 1) ? hB0 : hA0; float* hout0 = (s & 1) ? hA0 : hB0;
      float* hin1 = (s & 1) ? hB1 : hA1; float* hout1 = (s & 1) ? hA1 : hB1;
      ScanDir df, db_;
      df.xp = xpf; df.U = Uf; df.h_in = hin0; df.h_out = hout0; df.c = cS0;
      df.hs = nullptr; df.hs_bf = hs_bf; df.hT = hTc; df.cT = cTc;
      df.hs_off = 0; df.hs_pitch = 1024; df.t = s; df.cat_off = 0;
      db_.xp = xpb; db_.U = Ub; db_.h_in = hin1; db_.h_out = hout1; db_.c = cS1;
      db_.hs = nullptr; db_.hs_bf = hs_bf; db_.hT = hTc; db_.cT = cTc;
      db_.hs_off = 512; db_.hs_pitch = 1024; db_.t = Ssz - 1 - s; db_.cat_off = 512;
      // 256 thr: 32b x 2ks x 4jl -> JPB=4, grid.x = 512/4 = 128, grid.y = 2 dirs
      lstm_step_k<<<dim3(128, 2), 256, 0, stream>>>(df, db_, (s == Ssz - 1) ? 1 : 0);
    }
  };

  auto dec_scan = [&](const float* xp, const float* U, const float* h0p, const float* c0p,
                      float* hs, unsigned short* hs_bf) {
    hipMemcpyAsync(hA0, h0p, STATE_BYTES, hipMemcpyDeviceToDevice, stream);
    hipMemcpyAsync(cS0, c0p, STATE_BYTES, hipMemcpyDeviceToDevice, stream);
    for (int s = 0; s < Tsz; s++) {
      float* hin = (s & 1) ? hB0 : hA0; float* hout = (s & 1) ? hA0 : hB0;
      ScanDir d;
      d.xp = xp; d.U = U; d.h_in = hin; d.h_out = hout; d.c = cS0;
      d.hs = hs; d.hs_bf = hs_bf; d.hT = nullptr; d.cT = nullptr;
      d.hs_off = 0; d.hs_pitch = 512; d.t = s; d.cat_off = 0;
      // 128 thr: 32b x 2ks x 2jl -> JPB=2, grid.x = 512/2 = 256 (all CUs covered)
      lstm_step_k<<<dim3(256, 1), 128, 0, stream>>>(d, d, 0);
    }
  };

  // ---- weight conversions (independent; front-load them) ----
  cvt_bf16_k<<<32000, 256, 0, stream>>>(fcW, fcw_bf, (Vsz * 1024) / 4);
  cvtw(eW0f, eW0f_b, Gsz * Esz);
  cvtw(eW0b, eW0b_b, Gsz * Esz);
  cvtw(eW1f, eW1f_b, Gsz * 1024);
  cvtw(eW1b, eW1b_b, Gsz * 1024);
  cvtw(out_W, outW_b, Hsz * 1024);
  cvtw(dW0, dW0_b, Gsz * Esz);
  cvtw(dW1, dW1_b, Gsz * Hsz);

  embed_bf16_k<<<BT, 64, 0, stream>>>(src_seq, src_emb, x0b);
  embed_bf16_k<<<BT, 64, 0, stream>>>(trg_seq, trg_emb, y0b);

  // encoder layer 0 (xp via MFMA bf16)
  bgemm(x0b, eW0f_b, eb0f, xpA, BT, Gsz, Esz);
  bgemm(x0b, eW0b_b, eb0b, xpB, BT, Gsz, Esz);
  enc_scan(xpA, eU0f, xpB, eU0b, x1b, hT0, cT0);

  // encoder layer 1
  bgemm(x1b, eW1f_b, eb1f, xpA, BT, Gsz, 1024);
  bgemm(x1b, eW1b_b, eb1b, xpB, BT, Gsz, 1024);
  enc_scan(xpA, eU1f, xpB, eU1b, x2b, hT1, cT1);

  // encoder output projection + decoder initial states
  bgemm(x2b, outW_b, out_b, enc_out, BT, Hsz, 1024);
  gemm(hT0, hpW, hpb, h00, Bsz, Hsz, 1024);
  gemm(cT0, cpW, cpb, c00, Bsz, Hsz, 1024);
  gemm(hT1, hpW + (size_t)Hsz * 1024, hpb + Hsz, h01, Bsz, Hsz, 1024);
  gemm(cT1, cpW + (size_t)Hsz * 1024, cpb + Hsz, c01, Bsz, Hsz, 1024);

  // decoder layer 0
  bgemm(y0b, dW0_b, db0, xpA, BT, Gsz, Esz);
  dec_scan(xpA, dU0, h00, c00, nullptr, y1b);

  // decoder layer 1
  bgemm(y1b, dW1_b, db1, xpB, BT, Gsz, Hsz);
  dec_scan(xpB, dU1, h01, c01, y2, nullptr);

  // attention + output head
  attn_k<<<BT, 128, 0, stream>>>(y2, enc_out, src_seq, ctxb);
  build_comb_k<<<BT, 256, 0, stream>>>(y2, ctxb, comb_bf);
  gemm_bf16_k<<<dim3(Vsz / 128, BT / 128), 256, 0, stream>>>(comb_bf, fcw_bf, fcb, out,
                                                             BT, Vsz, 1024);
}